// Round 3
// baseline (829.290 us; speedup 1.0000x reference)
//
#include <hip/hip_runtime.h>
#include <stdint.h>

typedef unsigned int u32;
typedef unsigned short u16;
typedef __bf16 bf16x8 __attribute__((ext_vector_type(8)));
typedef float floatx16 __attribute__((ext_vector_type(16)));
typedef u32 u32x4 __attribute__((ext_vector_type(4)));

__device__ __forceinline__ u16 f2b(float f) {
    u32 u = __builtin_bit_cast(u32, f);
    u32 r = u + 0x7FFFu + ((u >> 16) & 1u);
    return (u16)(r >> 16);
}
__device__ __forceinline__ float lo2f(u32 u) { return __builtin_bit_cast(float, u << 16); }
__device__ __forceinline__ float hi2f(u32 u) { return __builtin_bit_cast(float, u & 0xFFFF0000u); }

// ---------------- runtime dtype detection ----------------
// flags[0] = edge_index is int64 (u32 hi-words all zero over first 64 pairs)
// flags[1] = floats are bf16 (low-16 of x's first 64 u32 words decode to
//            plausible bf16 exponents; fp32 mantissa bits fail w.p. ~1)

__global__ void detect_kernel(const int* __restrict__ ei, const u32* __restrict__ xw,
                              int* __restrict__ flags) {
    int lane = threadIdx.x;  // single wave of 64
    int v = ei[2 * lane + 1];
    unsigned long long b1 = __ballot(v == 0);
    u32 w = xw[lane];
    u32 e = (w >> 7) & 0xFF;
    int plaus = (e == 0) || (e >= 90 && e <= 140);
    unsigned long long b2 = __ballot(plaus);
    if (lane == 0) {
        flags[0] = (b1 == ~0ULL) ? 1 : 0;
        flags[1] = (b2 == ~0ULL) ? 1 : 0;
    }
}

__device__ __forceinline__ int load_id(const int* __restrict__ ei, int is64, size_t pos, int N) {
    int v = is64 ? ei[2 * pos] : ei[pos];
    unsigned u = (unsigned)v;
    if (u >= (unsigned)N) u = 0;  // clamp: never OOB
    return (int)u;
}

__device__ __forceinline__ float load_f(const void* __restrict__ p, int isbf, size_t i) {
    if (isbf) {
        u16 s = ((const u16*)p)[i];
        return __builtin_bit_cast(float, ((u32)s) << 16);
    }
    return ((const float*)p)[i];
}

// ---------------- conversion front-end ----------------

// x -> packed bf16 pairs (u32 words), count64 = N*64 words
__global__ void convert_x_kernel(const void* __restrict__ xraw, const int* __restrict__ flags,
                                 u32* __restrict__ xb, int count64) {
    int i = blockIdx.x * 256 + threadIdx.x;
    if (i >= count64) return;
    if (flags[1]) {
        xb[i] = ((const u32*)xraw)[i];
    } else {
        const float* f = (const float*)xraw;
        float f0 = f[2 * i], f1 = f[2 * i + 1];
        xb[i] = (u32)f2b(f0) | ((u32)f2b(f1) << 16);
    }
}

// biases + head weights -> fp32 smalls: [0,384) bl1|bl2|bl3, [384,640) Wo, [640,642) bo
__global__ void convert_smalls_kernel(const void* b0, const void* b1, const void* b2,
                                      const void* Wo, const void* bo,
                                      const int* __restrict__ flags, float* __restrict__ out) {
    int t = threadIdx.x;  // one block of 768
    int isbf = flags[1];
    if (t < 128) out[t] = load_f(b0, isbf, t);
    else if (t < 256) out[t] = load_f(b1, isbf, t - 128);
    else if (t < 384) out[t] = load_f(b2, isbf, t - 256);
    else if (t < 640) out[t] = load_f(Wo, isbf, t - 384);
    else if (t < 642) out[t] = load_f(bo, isbf, t - 640);
}

// ---------------- CSR build ----------------

__global__ void hist_kernel(const int* __restrict__ ei, int E, const int* __restrict__ flags,
                            int N, int* __restrict__ cnt) {
    int e = blockIdx.x * 256 + threadIdx.x;
    if (e >= E) return;
    int d = load_id(ei, flags[0], (size_t)E + e, N);
    atomicAdd(&cnt[d], 1);
}

__global__ void scan_blocks_kernel(const int* __restrict__ cnt, int N,
                                   int* __restrict__ local_excl, int* __restrict__ bsums,
                                   float* __restrict__ inv_deg) {
    __shared__ int wsum[4];
    int i = blockIdx.x * 256 + threadIdx.x;
    int lane = threadIdx.x & 63;
    int wid = threadIdx.x >> 6;
    int v = (i < N) ? cnt[i] : 0;
    int inc = v;
#pragma unroll
    for (int off = 1; off < 64; off <<= 1) {
        int o = __shfl_up(inc, off);
        if (lane >= off) inc += o;
    }
    if (lane == 63) wsum[wid] = inc;
    __syncthreads();
    int wprefix = 0;
    for (int w = 0; w < wid; ++w) wprefix += wsum[w];
    int excl = wprefix + inc - v;
    if (i < N) {
        local_excl[i] = excl;
        inv_deg[i] = 1.0f / (float)(v > 1 ? v : 1);
    }
    if (threadIdx.x == 255) bsums[blockIdx.x] = wprefix + inc;
}

__global__ void scan_sums_kernel(int* __restrict__ bsums, int nb) {
    int lane = threadIdx.x;  // single wave of 64
    int carry = 0;
    for (int base = 0; base < nb; base += 64) {
        int idx = base + lane;
        int v = (idx < nb) ? bsums[idx] : 0;
        int inc = v;
#pragma unroll
        for (int off = 1; off < 64; off <<= 1) {
            int o = __shfl_up(inc, off);
            if (lane >= off) inc += o;
        }
        if (idx < nb) bsums[idx] = carry + inc - v;
        carry += __shfl(inc, 63);
    }
}

__global__ void finalize_kernel(int* __restrict__ offsets, const int* __restrict__ bsums,
                                int N, int* __restrict__ cursor) {
    int i = blockIdx.x * 256 + threadIdx.x;
    if (i < N) {
        int off = offsets[i] + bsums[i >> 8];
        offsets[i] = off;
        cursor[i] = off;
    }
}

__global__ void fill_kernel(const int* __restrict__ ei, int E, const int* __restrict__ flags,
                            int N, int* __restrict__ cursor, int* __restrict__ csr_src) {
    int e = blockIdx.x * 256 + threadIdx.x;
    if (e >= E) return;
    int is64 = flags[0];
    int s = load_id(ei, is64, (size_t)e, N);
    int d = load_id(ei, is64, (size_t)E + e, N);
    int slot = atomicAdd(&cursor[d], 1);
    csr_src[slot] = s;
}

// ---------------- weight swizzle (B-fragment order, bf16 out) ----------------
// chunk t in [0,4096): lane=t&63, jt=(t>>6)&3, s=t>>8
// holds B[k = s*16 + (lane>>5)*8 + jj][j = jt*32 + (lane&31)], jj=0..7
// B[k][j] = (k<128) ? Wl[j][k] : Wr[j][k-128]

__global__ void wprep_kernel(const void* __restrict__ Wl, const void* __restrict__ Wr,
                             const int* __restrict__ flags, u16* __restrict__ Wcp) {
    int t = blockIdx.x * 256 + threadIdx.x;  // 0..4095
    int isbf = flags[1];
    int lane = t & 63;
    int jt = (t >> 6) & 3;
    int s = t >> 8;
    int n = lane & 31;
    int q = lane >> 5;
    int j = jt * 32 + n;
#pragma unroll
    for (int jj = 0; jj < 8; ++jj) {
        int k = s * 16 + q * 8 + jj;
        float v = (k < 128) ? load_f(Wl, isbf, (size_t)j * 128 + k)
                            : load_f(Wr, isbf, (size_t)j * 128 + (k - 128));
        Wcp[t * 8 + jj] = f2b(v);
    }
}

// ---------------- fused layer: agg (LDS) + dual-GEMM ----------------
// block=256 (4 waves) handles 128 nodes. Stage1: mean-agg into LDS
// (row stride 66 u32: 2-way bank aliasing = free per m136).
// Stage2: H = act(concat(agg,F) @ Wc + b), 16 k-steps mfma_f32_32x32x16_bf16.

#define ROWW 66

__global__ void layer_kernel(const u32* __restrict__ F2, const int* __restrict__ offsets,
                             const int* __restrict__ cnt, const float* __restrict__ inv_deg,
                             const int* __restrict__ csr, const u16* __restrict__ Wcp,
                             const float* __restrict__ biasf, u32* __restrict__ Hout,
                             int N, int relu) {
    __shared__ u32 aggs[128 * ROWW];  // 33792 B
    int tid = threadIdx.x;
    int w = tid >> 6;
    int lane = tid & 63;
    int nbase = blockIdx.x * 128;

    // stage 1: wave w aggregates nodes [w*32, w*32+32)
    for (int l = w * 32; l < w * 32 + 32; ++l) {
        int node = nbase + l;
        float a0 = 0.f, a1 = 0.f;
        if (node < N) {
            int start = offsets[node];
            int num = cnt[node];
            for (int i = 0; i < num; ++i) {
                int sidx = csr[start + i];
                u32 u = F2[(size_t)sidx * 64 + lane];
                a0 += lo2f(u);
                a1 += hi2f(u);
            }
            float sc = inv_deg[node];
            a0 *= sc;
            a1 *= sc;
        }
        aggs[l * ROWW + lane] = (u32)f2b(a0) | ((u32)f2b(a1) << 16);
    }
    __syncthreads();

    // stage 2: GEMM. A row m=lane&31 (this wave's 32 nodes), k-half q=lane>>5.
    int n = lane & 31;
    int q = lane >> 5;
    int rowl = w * 32 + n;
    int node = nbase + rowl;
    int nodeC = (node < N) ? node : (N - 1);
    const u32* fRow = F2 + (size_t)nodeC * 64 + q * 4;

    floatx16 acc0 = 0.0f, acc1 = 0.0f, acc2 = 0.0f, acc3 = 0.0f;

#pragma unroll
    for (int s = 0; s < 16; ++s) {
        bf16x8 a;
        if (s < 8) {
            const u32* p = &aggs[rowl * ROWW + s * 8 + q * 4];
            u32x4 t;
            t.x = p[0];
            t.y = p[1];
            t.z = p[2];
            t.w = p[3];
            a = __builtin_bit_cast(bf16x8, t);
        } else {
            a = *reinterpret_cast<const bf16x8*>(fRow + (size_t)(s - 8) * 8);
        }
        const u16* bp = Wcp + (size_t)((s * 4) * 64 + lane) * 8;
        bf16x8 b0 = *reinterpret_cast<const bf16x8*>(bp);
        bf16x8 b1 = *reinterpret_cast<const bf16x8*>(bp + 64 * 8);
        bf16x8 b2 = *reinterpret_cast<const bf16x8*>(bp + 2 * 64 * 8);
        bf16x8 b3 = *reinterpret_cast<const bf16x8*>(bp + 3 * 64 * 8);
        acc0 = __builtin_amdgcn_mfma_f32_32x32x16_bf16(a, b0, acc0, 0, 0, 0);
        acc1 = __builtin_amdgcn_mfma_f32_32x32x16_bf16(a, b1, acc1, 0, 0, 0);
        acc2 = __builtin_amdgcn_mfma_f32_32x32x16_bf16(a, b2, acc2, 0, 0, 0);
        acc3 = __builtin_amdgcn_mfma_f32_32x32x16_bf16(a, b3, acc3, 0, 0, 0);
    }

    int mbase = nbase + w * 32;
    floatx16 accs[4] = {acc0, acc1, acc2, acc3};
    // C/D: col=lane&31, row=(r&3)+8*(r>>2)+4*(lane>>5)  [verified m74/m101]
#pragma unroll
    for (int jt = 0; jt < 4; ++jt) {
        int j0 = jt * 32 + n;
        float bf = biasf[j0];
#pragma unroll
        for (int r = 0; r < 16; ++r) {
            int row = (r & 3) + 8 * (r >> 2) + 4 * q;
            int nodeS = mbase + row;
            if (nodeS < N) {
                float v = accs[jt][r] + bf;
                if (relu) v = fmaxf(v, 0.0f);
                u16 hv = f2b(v);
                u16* dst16 = (u16*)&Hout[(size_t)nodeS * 64];
                dst16[j0] = hv;
            }
        }
    }
}

// ---------------- output head: one wave per node ----------------

__global__ void head_kernel(const u32* __restrict__ h3, const float* __restrict__ smalls,
                            const int* __restrict__ flags, void* __restrict__ out, int N) {
    int gw = (blockIdx.x * 256 + threadIdx.x) >> 6;
    int lane = threadIdx.x & 63;
    if (gw >= N) return;
    const float* Wof = smalls + 384;
    u32 hv = h3[(size_t)gw * 64 + lane];
    float h0 = lo2f(hv), h1 = hi2f(hv);
    float p0 = h0 * Wof[2 * lane] + h1 * Wof[2 * lane + 1];
    float p1 = h0 * Wof[128 + 2 * lane] + h1 * Wof[128 + 2 * lane + 1];
#pragma unroll
    for (int off = 32; off > 0; off >>= 1) {
        p0 += __shfl_xor(p0, off);
        p1 += __shfl_xor(p1, off);
    }
    if (lane == 0) {
        p0 += smalls[640];
        p1 += smalls[641];
        if (flags[1]) {
            ((u32*)out)[gw] = (u32)f2b(p0) | ((u32)f2b(p1) << 16);
        } else {
            ((float2*)out)[gw] = make_float2(p0, p1);
        }
    }
}

extern "C" void kernel_launch(void* const* d_in, const int* in_sizes, int n_in,
                              void* d_out, int out_size, void* d_ws, size_t ws_size,
                              hipStream_t stream) {
    const int N = in_sizes[0] / 128;
    const int E = in_sizes[1] / 2;

    const void* x = d_in[0];
    const int* ei = (const int*)d_in[1];
    const void* Wl[3] = {d_in[2], d_in[5], d_in[8]};
    const void* bl[3] = {d_in[3], d_in[6], d_in[9]};
    const void* Wr[3] = {d_in[4], d_in[7], d_in[10]};
    const void* Wo = d_in[11];
    const void* bo = d_in[12];

    // workspace bump allocator (256B aligned); total ~57 MB
    char* p = (char*)d_ws;
    auto alloc = [&](size_t bytes) -> char* {
        char* r = p;
        p += (bytes + 255) & ~(size_t)255;
        return r;
    };
    int* flags = (int*)alloc(256);
    int* cnt = (int*)alloc((size_t)N * 4);
    int* offs = (int*)alloc((size_t)N * 4);
    int* cursor = (int*)alloc((size_t)N * 4);
    float* invd = (float*)alloc((size_t)N * 4);
    int* bsums = (int*)alloc(2048);
    float* smalls = (float*)alloc(642 * 4);
    int* csr = (int*)alloc((size_t)E * 4);
    u16* Wcp = (u16*)alloc((size_t)3 * 4096 * 8 * 2);
    u32* xb = (u32*)alloc((size_t)N * 64 * 4);  // also reused as hB
    u32* hA = (u32*)alloc((size_t)N * 64 * 4);
    (void)ws_size;

    const int nb = (N + 255) / 256;
    const int eb = (E + 255) / 256;
    const int wb = (N + 3) / 4;      // wave-per-node kernels
    const int gb = (N + 127) / 128;  // layer blocks
    const int cb = (N * 64 + 255) / 256;

    detect_kernel<<<1, 64, 0, stream>>>(ei, (const u32*)x, flags);
    hipMemsetAsync(cnt, 0, (size_t)N * 4, stream);
    hist_kernel<<<eb, 256, 0, stream>>>(ei, E, flags, N, cnt);
    scan_blocks_kernel<<<nb, 256, 0, stream>>>(cnt, N, offs, bsums, invd);
    scan_sums_kernel<<<1, 64, 0, stream>>>(bsums, nb);
    finalize_kernel<<<nb, 256, 0, stream>>>(offs, bsums, N, cursor);
    fill_kernel<<<eb, 256, 0, stream>>>(ei, E, flags, N, cursor, csr);

    convert_x_kernel<<<cb, 256, 0, stream>>>(x, flags, xb, N * 64);
    convert_smalls_kernel<<<1, 768, 0, stream>>>(bl[0], bl[1], bl[2], Wo, bo, flags, smalls);
    for (int l = 0; l < 3; ++l)
        wprep_kernel<<<16, 256, 0, stream>>>(Wl[l], Wr[l], flags, Wcp + (size_t)l * 32768);

    // layer 1: xb -> hA ; layer 2: hA -> xb (reuse) ; layer 3: xb -> hA
    layer_kernel<<<gb, 256, 0, stream>>>(xb, offs, cnt, invd, csr, Wcp, smalls, hA, N, 1);
    layer_kernel<<<gb, 256, 0, stream>>>(hA, offs, cnt, invd, csr, Wcp + 32768, smalls + 128, xb, N, 1);
    layer_kernel<<<gb, 256, 0, stream>>>(xb, offs, cnt, invd, csr, Wcp + 65536, smalls + 256, hA, N, 0);
    head_kernel<<<wb, 256, 0, stream>>>(hA, smalls, flags, d_out, N);
}

// Round 4
// 528.994 us; speedup vs baseline: 1.5677x; 1.5677x over previous
//
#include <hip/hip_runtime.h>
#include <stdint.h>

typedef unsigned int u32;
typedef unsigned short u16;
typedef __bf16 bf16x8 __attribute__((ext_vector_type(8)));
typedef float floatx16 __attribute__((ext_vector_type(16)));
typedef u32 u32x4 __attribute__((ext_vector_type(4)));

__device__ __forceinline__ u16 f2b(float f) {
    u32 u = __builtin_bit_cast(u32, f);
    u32 r = u + 0x7FFFu + ((u >> 16) & 1u);
    return (u16)(r >> 16);
}
__device__ __forceinline__ float lo2f(u32 u) { return __builtin_bit_cast(float, u << 16); }
__device__ __forceinline__ float hi2f(u32 u) { return __builtin_bit_cast(float, u & 0xFFFF0000u); }

// ---------------- runtime dtype detection ----------------
// flags[0] = edge_index is int64; flags[1] = floats are bf16

__global__ void detect_kernel(const int* __restrict__ ei, const u32* __restrict__ xw,
                              int* __restrict__ flags) {
    int lane = threadIdx.x;  // single wave of 64
    int v = ei[2 * lane + 1];
    unsigned long long b1 = __ballot(v == 0);
    u32 w = xw[lane];
    u32 e = (w >> 7) & 0xFF;
    int plaus = (e == 0) || (e >= 90 && e <= 140);
    unsigned long long b2 = __ballot(plaus);
    if (lane == 0) {
        flags[0] = (b1 == ~0ULL) ? 1 : 0;
        flags[1] = (b2 == ~0ULL) ? 1 : 0;
    }
}

__device__ __forceinline__ int load_id(const int* __restrict__ ei, int is64, size_t pos, int N) {
    int v = is64 ? ei[2 * pos] : ei[pos];
    unsigned u = (unsigned)v;
    if (u >= (unsigned)N) u = 0;  // clamp: never OOB
    return (int)u;
}

__device__ __forceinline__ float load_f(const void* __restrict__ p, int isbf, size_t i) {
    if (isbf) {
        u16 s = ((const u16*)p)[i];
        return __builtin_bit_cast(float, ((u32)s) << 16);
    }
    return ((const float*)p)[i];
}

// ---------------- conversion front-end ----------------

__global__ void convert_x_kernel(const void* __restrict__ xraw, const int* __restrict__ flags,
                                 u32* __restrict__ xb, int count64) {
    int i = blockIdx.x * 256 + threadIdx.x;
    if (i >= count64) return;
    if (flags[1]) {
        xb[i] = ((const u32*)xraw)[i];
    } else {
        const float* f = (const float*)xraw;
        xb[i] = (u32)f2b(f[2 * i]) | ((u32)f2b(f[2 * i + 1]) << 16);
    }
}

// fp32 smalls: [0,384) bl1|bl2|bl3, [384,640) Wo, [640,642) bo
__global__ void convert_smalls_kernel(const void* b0, const void* b1, const void* b2,
                                      const void* Wo, const void* bo,
                                      const int* __restrict__ flags, float* __restrict__ out) {
    int t = threadIdx.x;  // one block of 768
    int isbf = flags[1];
    if (t < 128) out[t] = load_f(b0, isbf, t);
    else if (t < 256) out[t] = load_f(b1, isbf, t - 128);
    else if (t < 384) out[t] = load_f(b2, isbf, t - 256);
    else if (t < 640) out[t] = load_f(Wo, isbf, t - 384);
    else if (t < 642) out[t] = load_f(bo, isbf, t - 640);
}

// ---------------- CSR build ----------------

__global__ void hist_kernel(const int* __restrict__ ei, int E, const int* __restrict__ flags,
                            int N, int* __restrict__ cnt) {
    int e = blockIdx.x * 256 + threadIdx.x;
    if (e >= E) return;
    int d = load_id(ei, flags[0], (size_t)E + e, N);
    atomicAdd(&cnt[d], 1);
}

__global__ void scan_blocks_kernel(const int* __restrict__ cnt, int N,
                                   int* __restrict__ local_excl, int* __restrict__ bsums,
                                   float* __restrict__ inv_deg) {
    __shared__ int wsum[4];
    int i = blockIdx.x * 256 + threadIdx.x;
    int lane = threadIdx.x & 63;
    int wid = threadIdx.x >> 6;
    int v = (i < N) ? cnt[i] : 0;
    int inc = v;
#pragma unroll
    for (int off = 1; off < 64; off <<= 1) {
        int o = __shfl_up(inc, off);
        if (lane >= off) inc += o;
    }
    if (lane == 63) wsum[wid] = inc;
    __syncthreads();
    int wprefix = 0;
    for (int w = 0; w < wid; ++w) wprefix += wsum[w];
    int excl = wprefix + inc - v;
    if (i < N) {
        local_excl[i] = excl;
        inv_deg[i] = 1.0f / (float)(v > 1 ? v : 1);
    }
    if (threadIdx.x == 255) bsums[blockIdx.x] = wprefix + inc;
}

__global__ void scan_sums_kernel(int* __restrict__ bsums, int nb) {
    int lane = threadIdx.x;  // single wave of 64
    int carry = 0;
    for (int base = 0; base < nb; base += 64) {
        int idx = base + lane;
        int v = (idx < nb) ? bsums[idx] : 0;
        int inc = v;
#pragma unroll
        for (int off = 1; off < 64; off <<= 1) {
            int o = __shfl_up(inc, off);
            if (lane >= off) inc += o;
        }
        if (idx < nb) bsums[idx] = carry + inc - v;
        carry += __shfl(inc, 63);
    }
}

__global__ void finalize_kernel(int* __restrict__ offsets, const int* __restrict__ bsums,
                                int N, int* __restrict__ cursor) {
    int i = blockIdx.x * 256 + threadIdx.x;
    if (i < N) {
        int off = offsets[i] + bsums[i >> 8];
        offsets[i] = off;
        cursor[i] = off;
    }
}

__global__ void fill_kernel(const int* __restrict__ ei, int E, const int* __restrict__ flags,
                            int N, int* __restrict__ cursor, int* __restrict__ csr_src) {
    int e = blockIdx.x * 256 + threadIdx.x;
    if (e >= E) return;
    int is64 = flags[0];
    int s = load_id(ei, is64, (size_t)e, N);
    int d = load_id(ei, is64, (size_t)E + e, N);
    int slot = atomicAdd(&cursor[d], 1);
    csr_src[slot] = s;
}

// ---------------- weight swizzle (B-fragment order, bf16 out) ----------------

__global__ void wprep_kernel(const void* __restrict__ Wl, const void* __restrict__ Wr,
                             const int* __restrict__ flags, u16* __restrict__ Wcp) {
    int t = blockIdx.x * 256 + threadIdx.x;  // 0..4095
    int isbf = flags[1];
    int lane = t & 63;
    int jt = (t >> 6) & 3;
    int s = t >> 8;
    int n = lane & 31;
    int q = lane >> 5;
    int j = jt * 32 + n;
#pragma unroll
    for (int jj = 0; jj < 8; ++jj) {
        int k = s * 16 + q * 8 + jj;
        float v = (k < 128) ? load_f(Wl, isbf, (size_t)j * 128 + k)
                            : load_f(Wr, isbf, (size_t)j * 128 + (k - 128));
        Wcp[t * 8 + jj] = f2b(v);
    }
}

// ---------------- fused layer: agg (LDS) + dual-GEMM (+ optional head) ----------------
// block=256 (4 waves) handles 128 nodes. Stage1: mean-agg into LDS with
// 8/4/1-deep batched neighbor loads (MLP: 8 row-loads in flight per lane).
// Stage2: H = act(concat(agg,F) @ Wc + b), 16 k-steps mfma_f32_32x32x16_bf16.
// If outp != nullptr (last layer): fuse output head, no H store.

#define ROWW 66

__global__ void layer_kernel(const u32* __restrict__ F2, const int* __restrict__ offsets,
                             const int* __restrict__ cnt, const float* __restrict__ inv_deg,
                             const int* __restrict__ csr, const u16* __restrict__ Wcp,
                             const float* __restrict__ biasf, u32* __restrict__ Hout,
                             int N, int relu, const float* __restrict__ headw,
                             const int* __restrict__ flags, void* __restrict__ outp) {
    __shared__ u32 aggs[128 * ROWW];  // 33792 B
    int tid = threadIdx.x;
    int w = tid >> 6;
    int lane = tid & 63;
    int nbase = blockIdx.x * 128;

    // stage 1: wave w aggregates nodes [w*32, w*32+32)
    for (int l = w * 32; l < w * 32 + 32; ++l) {
        int node = nbase + l;
        float a0 = 0.f, a1 = 0.f;
        if (node < N) {
            int start = offsets[node];
            int num = cnt[node];
            int i = 0;
            for (; i + 8 <= num; i += 8) {
                int s0 = csr[start + i + 0], s1 = csr[start + i + 1];
                int s2 = csr[start + i + 2], s3 = csr[start + i + 3];
                int s4 = csr[start + i + 4], s5 = csr[start + i + 5];
                int s6 = csr[start + i + 6], s7 = csr[start + i + 7];
                u32 u0 = F2[(size_t)s0 * 64 + lane];
                u32 u1 = F2[(size_t)s1 * 64 + lane];
                u32 u2 = F2[(size_t)s2 * 64 + lane];
                u32 u3 = F2[(size_t)s3 * 64 + lane];
                u32 u4 = F2[(size_t)s4 * 64 + lane];
                u32 u5 = F2[(size_t)s5 * 64 + lane];
                u32 u6 = F2[(size_t)s6 * 64 + lane];
                u32 u7 = F2[(size_t)s7 * 64 + lane];
                a0 += lo2f(u0) + lo2f(u1) + lo2f(u2) + lo2f(u3) +
                      lo2f(u4) + lo2f(u5) + lo2f(u6) + lo2f(u7);
                a1 += hi2f(u0) + hi2f(u1) + hi2f(u2) + hi2f(u3) +
                      hi2f(u4) + hi2f(u5) + hi2f(u6) + hi2f(u7);
            }
            for (; i + 4 <= num; i += 4) {
                int s0 = csr[start + i + 0], s1 = csr[start + i + 1];
                int s2 = csr[start + i + 2], s3 = csr[start + i + 3];
                u32 u0 = F2[(size_t)s0 * 64 + lane];
                u32 u1 = F2[(size_t)s1 * 64 + lane];
                u32 u2 = F2[(size_t)s2 * 64 + lane];
                u32 u3 = F2[(size_t)s3 * 64 + lane];
                a0 += lo2f(u0) + lo2f(u1) + lo2f(u2) + lo2f(u3);
                a1 += hi2f(u0) + hi2f(u1) + hi2f(u2) + hi2f(u3);
            }
            for (; i < num; ++i) {
                u32 u = F2[(size_t)csr[start + i] * 64 + lane];
                a0 += lo2f(u);
                a1 += hi2f(u);
            }
            float sc = inv_deg[node];
            a0 *= sc;
            a1 *= sc;
        }
        aggs[l * ROWW + lane] = (u32)f2b(a0) | ((u32)f2b(a1) << 16);
    }
    __syncthreads();

    // stage 2: GEMM. A row m=lane&31, k-half q=lane>>5.
    int n = lane & 31;
    int q = lane >> 5;
    int rowl = w * 32 + n;
    int node = nbase + rowl;
    int nodeC = (node < N) ? node : (N - 1);
    const u32* fRow = F2 + (size_t)nodeC * 64 + q * 4;

    floatx16 acc0 = 0.0f, acc1 = 0.0f, acc2 = 0.0f, acc3 = 0.0f;

#pragma unroll
    for (int s = 0; s < 16; ++s) {
        bf16x8 a;
        if (s < 8) {
            const u32* p = &aggs[rowl * ROWW + s * 8 + q * 4];
            u32x4 t;
            t.x = p[0];
            t.y = p[1];
            t.z = p[2];
            t.w = p[3];
            a = __builtin_bit_cast(bf16x8, t);
        } else {
            a = *reinterpret_cast<const bf16x8*>(fRow + (size_t)(s - 8) * 8);
        }
        const u16* bp = Wcp + (size_t)((s * 4) * 64 + lane) * 8;
        bf16x8 b0 = *reinterpret_cast<const bf16x8*>(bp);
        bf16x8 b1 = *reinterpret_cast<const bf16x8*>(bp + 64 * 8);
        bf16x8 b2 = *reinterpret_cast<const bf16x8*>(bp + 2 * 64 * 8);
        bf16x8 b3 = *reinterpret_cast<const bf16x8*>(bp + 3 * 64 * 8);
        acc0 = __builtin_amdgcn_mfma_f32_32x32x16_bf16(a, b0, acc0, 0, 0, 0);
        acc1 = __builtin_amdgcn_mfma_f32_32x32x16_bf16(a, b1, acc1, 0, 0, 0);
        acc2 = __builtin_amdgcn_mfma_f32_32x32x16_bf16(a, b2, acc2, 0, 0, 0);
        acc3 = __builtin_amdgcn_mfma_f32_32x32x16_bf16(a, b3, acc3, 0, 0, 0);
    }

    int mbase = nbase + w * 32;
    floatx16 accs[4] = {acc0, acc1, acc2, acc3};
    // C/D: col=lane&31, row=(r&3)+8*(r>>2)+4*(lane>>5)  [verified m74/m101]

    if (outp == nullptr) {
#pragma unroll
        for (int jt = 0; jt < 4; ++jt) {
            int j0 = jt * 32 + n;
            float bf = biasf[j0];
#pragma unroll
            for (int r = 0; r < 16; ++r) {
                int row = (r & 3) + 8 * (r >> 2) + 4 * q;
                int nodeS = mbase + row;
                if (nodeS < N) {
                    float v = accs[jt][r] + bf;
                    if (relu) v = fmaxf(v, 0.0f);
                    u16* dst16 = (u16*)&Hout[(size_t)nodeS * 64];
                    dst16[j0] = f2b(v);
                }
            }
        }
    } else {
        // fused head: out[node] = (h·Wo0 + bo0, h·Wo1 + bo1); h = acc + bl3
        int isbf = flags[1];
#pragma unroll
        for (int r = 0; r < 16; ++r) {
            float p0 = 0.f, p1 = 0.f;
#pragma unroll
            for (int jt = 0; jt < 4; ++jt) {
                int j = jt * 32 + n;
                float v = accs[jt][r] + biasf[j];
                p0 += v * headw[j];
                p1 += v * headw[128 + j];
            }
            // reduce over n (bits 0..4) — q-halves hold disjoint rows
#pragma unroll
            for (int off = 16; off > 0; off >>= 1) {
                p0 += __shfl_xor(p0, off);
                p1 += __shfl_xor(p1, off);
            }
            if (n == 0) {
                int row = (r & 3) + 8 * (r >> 2) + 4 * q;
                int nodeS = mbase + row;
                if (nodeS < N) {
                    float o0 = p0 + headw[256];  // bo0
                    float o1 = p1 + headw[257];  // bo1
                    if (isbf)
                        ((u32*)outp)[nodeS] = (u32)f2b(o0) | ((u32)f2b(o1) << 16);
                    else
                        ((float2*)outp)[nodeS] = make_float2(o0, o1);
                }
            }
        }
    }
}

extern "C" void kernel_launch(void* const* d_in, const int* in_sizes, int n_in,
                              void* d_out, int out_size, void* d_ws, size_t ws_size,
                              hipStream_t stream) {
    const int N = in_sizes[0] / 128;
    const int E = in_sizes[1] / 2;

    const void* x = d_in[0];
    const int* ei = (const int*)d_in[1];
    const void* Wl[3] = {d_in[2], d_in[5], d_in[8]};
    const void* bl[3] = {d_in[3], d_in[6], d_in[9]};
    const void* Wr[3] = {d_in[4], d_in[7], d_in[10]};
    const void* Wo = d_in[11];
    const void* bo = d_in[12];

    // workspace bump allocator (256B aligned); total ~57 MB
    char* p = (char*)d_ws;
    auto alloc = [&](size_t bytes) -> char* {
        char* r = p;
        p += (bytes + 255) & ~(size_t)255;
        return r;
    };
    int* flags = (int*)alloc(256);
    int* cnt = (int*)alloc((size_t)N * 4);
    int* offs = (int*)alloc((size_t)N * 4);
    int* cursor = (int*)alloc((size_t)N * 4);
    float* invd = (float*)alloc((size_t)N * 4);
    int* bsums = (int*)alloc(2048);
    float* smalls = (float*)alloc(642 * 4);
    int* csr = (int*)alloc((size_t)E * 4);
    u16* Wcp = (u16*)alloc((size_t)3 * 4096 * 8 * 2);
    u32* xb = (u32*)alloc((size_t)N * 64 * 4);  // also reused as hB
    u32* hA = (u32*)alloc((size_t)N * 64 * 4);
    (void)ws_size;

    const int nb = (N + 255) / 256;
    const int eb = (E + 255) / 256;
    const int gb = (N + 127) / 128;  // layer blocks
    const int cb = (N * 64 + 255) / 256;

    detect_kernel<<<1, 64, 0, stream>>>(ei, (const u32*)x, flags);
    hipMemsetAsync(cnt, 0, (size_t)N * 4, stream);
    hist_kernel<<<eb, 256, 0, stream>>>(ei, E, flags, N, cnt);
    scan_blocks_kernel<<<nb, 256, 0, stream>>>(cnt, N, offs, bsums, invd);
    scan_sums_kernel<<<1, 64, 0, stream>>>(bsums, nb);
    finalize_kernel<<<nb, 256, 0, stream>>>(offs, bsums, N, cursor);
    fill_kernel<<<eb, 256, 0, stream>>>(ei, E, flags, N, cursor, csr);

    convert_x_kernel<<<cb, 256, 0, stream>>>(x, flags, xb, N * 64);
    convert_smalls_kernel<<<1, 768, 0, stream>>>(bl[0], bl[1], bl[2], Wo, bo, flags, smalls);
    for (int l = 0; l < 3; ++l)
        wprep_kernel<<<16, 256, 0, stream>>>(Wl[l], Wr[l], flags, Wcp + (size_t)l * 32768);

    // layer 1: xb -> hA ; layer 2: hA -> xb ; layer 3+head: xb -> d_out
    layer_kernel<<<gb, 256, 0, stream>>>(xb, offs, cnt, invd, csr, Wcp, smalls, hA, N, 1,
                                         nullptr, flags, nullptr);
    layer_kernel<<<gb, 256, 0, stream>>>(hA, offs, cnt, invd, csr, Wcp + 32768, smalls + 128,
                                         xb, N, 1, nullptr, flags, nullptr);
    layer_kernel<<<gb, 256, 0, stream>>>(xb, offs, cnt, invd, csr, Wcp + 65536, smalls + 256,
                                         hA, N, 0, smalls + 384, flags, d_out);
}

// Round 5
// 444.802 us; speedup vs baseline: 1.8644x; 1.1893x over previous
//
#include <hip/hip_runtime.h>
#include <stdint.h>

typedef unsigned int u32;
typedef unsigned short u16;
typedef __bf16 bf16x8 __attribute__((ext_vector_type(8)));
typedef float floatx16 __attribute__((ext_vector_type(16)));
typedef u32 u32x4 __attribute__((ext_vector_type(4)));
typedef float floatx4 __attribute__((ext_vector_type(4)));

__device__ __forceinline__ u16 f2b(float f) {
    u32 u = __builtin_bit_cast(u32, f);
    u32 r = u + 0x7FFFu + ((u >> 16) & 1u);
    return (u16)(r >> 16);
}
__device__ __forceinline__ float lo2f(u32 u) { return __builtin_bit_cast(float, u << 16); }
__device__ __forceinline__ float hi2f(u32 u) { return __builtin_bit_cast(float, u & 0xFFFF0000u); }

// ---------------- runtime dtype detection ----------------
// flags[0] = edge_index is int64; flags[1] = floats are bf16

__global__ void detect_kernel(const int* __restrict__ ei, const u32* __restrict__ xw,
                              int* __restrict__ flags) {
    int lane = threadIdx.x;  // single wave of 64
    int v = ei[2 * lane + 1];
    unsigned long long b1 = __ballot(v == 0);
    u32 w = xw[lane];
    u32 e = (w >> 7) & 0xFF;
    int plaus = (e == 0) || (e >= 90 && e <= 140);
    unsigned long long b2 = __ballot(plaus);
    if (lane == 0) {
        flags[0] = (b1 == ~0ULL) ? 1 : 0;
        flags[1] = (b2 == ~0ULL) ? 1 : 0;
    }
}

__device__ __forceinline__ int load_id(const int* __restrict__ ei, int is64, size_t pos, int N) {
    int v = is64 ? ei[2 * pos] : ei[pos];
    unsigned u = (unsigned)v;
    if (u >= (unsigned)N) u = 0;  // clamp: never OOB
    return (int)u;
}

__device__ __forceinline__ float load_f(const void* __restrict__ p, int isbf, size_t i) {
    if (isbf) {
        u16 s = ((const u16*)p)[i];
        return __builtin_bit_cast(float, ((u32)s) << 16);
    }
    return ((const float*)p)[i];
}

// ---------------- conversion front-end ----------------
// thread i handles 4 u32 outputs (8 bf16): 32B fp32 read / 16B write

__global__ void convert_x_kernel(const void* __restrict__ xraw, const int* __restrict__ flags,
                                 u32* __restrict__ xb, int count4) {
    int i = blockIdx.x * 256 + threadIdx.x;
    if (i >= count4) return;
    if (flags[1]) {
        ((u32x4*)xb)[i] = ((const u32x4*)xraw)[i];
    } else {
        const floatx4* f4 = (const floatx4*)xraw;
        floatx4 f0 = f4[2 * i], f1 = f4[2 * i + 1];
        u32x4 o;
        o.x = (u32)f2b(f0.x) | ((u32)f2b(f0.y) << 16);
        o.y = (u32)f2b(f0.z) | ((u32)f2b(f0.w) << 16);
        o.z = (u32)f2b(f1.x) | ((u32)f2b(f1.y) << 16);
        o.w = (u32)f2b(f1.z) | ((u32)f2b(f1.w) << 16);
        ((u32x4*)xb)[i] = o;
    }
}

// fp32 smalls: [0,384) bl1|bl2|bl3, [384,640) Wo, [640,642) bo
__global__ void convert_smalls_kernel(const void* b0, const void* b1, const void* b2,
                                      const void* Wo, const void* bo,
                                      const int* __restrict__ flags, float* __restrict__ out) {
    int t = threadIdx.x;  // one block of 768
    int isbf = flags[1];
    if (t < 128) out[t] = load_f(b0, isbf, t);
    else if (t < 256) out[t] = load_f(b1, isbf, t - 128);
    else if (t < 384) out[t] = load_f(b2, isbf, t - 256);
    else if (t < 640) out[t] = load_f(Wo, isbf, t - 384);
    else if (t < 642) out[t] = load_f(bo, isbf, t - 640);
}

// ---------------- CSR build ----------------

__global__ void hist_kernel(const int* __restrict__ ei, int E, const int* __restrict__ flags,
                            int N, int* __restrict__ cnt) {
    int e = blockIdx.x * 256 + threadIdx.x;
    if (e >= E) return;
    int d = load_id(ei, flags[0], (size_t)E + e, N);
    atomicAdd(&cnt[d], 1);
}

__global__ void scan_blocks_kernel(const int* __restrict__ cnt, int N,
                                   int* __restrict__ local_excl, int* __restrict__ bsums,
                                   float* __restrict__ inv_deg) {
    __shared__ int wsum[4];
    int i = blockIdx.x * 256 + threadIdx.x;
    int lane = threadIdx.x & 63;
    int wid = threadIdx.x >> 6;
    int v = (i < N) ? cnt[i] : 0;
    int inc = v;
#pragma unroll
    for (int off = 1; off < 64; off <<= 1) {
        int o = __shfl_up(inc, off);
        if (lane >= off) inc += o;
    }
    if (lane == 63) wsum[wid] = inc;
    __syncthreads();
    int wprefix = 0;
    for (int w = 0; w < wid; ++w) wprefix += wsum[w];
    int excl = wprefix + inc - v;
    if (i < N) {
        local_excl[i] = excl;
        inv_deg[i] = 1.0f / (float)(v > 1 ? v : 1);
    }
    if (threadIdx.x == 255) bsums[blockIdx.x] = wprefix + inc;
}

__global__ void scan_sums_kernel(int* __restrict__ bsums, int nb) {
    int lane = threadIdx.x;  // single wave of 64
    int carry = 0;
    for (int base = 0; base < nb; base += 64) {
        int idx = base + lane;
        int v = (idx < nb) ? bsums[idx] : 0;
        int inc = v;
#pragma unroll
        for (int off = 1; off < 64; off <<= 1) {
            int o = __shfl_up(inc, off);
            if (lane >= off) inc += o;
        }
        if (idx < nb) bsums[idx] = carry + inc - v;
        carry += __shfl(inc, 63);
    }
}

__global__ void finalize_kernel(int* __restrict__ offsets, const int* __restrict__ bsums,
                                int N, int* __restrict__ cursor) {
    int i = blockIdx.x * 256 + threadIdx.x;
    if (i < N) {
        int off = offsets[i] + bsums[i >> 8];
        offsets[i] = off;
        cursor[i] = off;
    }
}

__global__ void fill_kernel(const int* __restrict__ ei, int E, const int* __restrict__ flags,
                            int N, int* __restrict__ cursor, int* __restrict__ csr_src) {
    int e = blockIdx.x * 256 + threadIdx.x;
    if (e >= E) return;
    int is64 = flags[0];
    int s = load_id(ei, is64, (size_t)e, N);
    int d = load_id(ei, is64, (size_t)E + e, N);
    int slot = atomicAdd(&cursor[d], 1);
    csr_src[slot] = s;
}

// ---------------- weight swizzle (B-fragment order, bf16 out) ----------------

__global__ void wprep_kernel(const void* __restrict__ Wl, const void* __restrict__ Wr,
                             const int* __restrict__ flags, u16* __restrict__ Wcp) {
    int t = blockIdx.x * 256 + threadIdx.x;  // 0..4095
    int isbf = flags[1];
    int lane = t & 63;
    int jt = (t >> 6) & 3;
    int s = t >> 8;
    int n = lane & 31;
    int q = lane >> 5;
    int j = jt * 32 + n;
#pragma unroll
    for (int jj = 0; jj < 8; ++jj) {
        int k = s * 16 + q * 8 + jj;
        float v = (k < 128) ? load_f(Wl, isbf, (size_t)j * 128 + k)
                            : load_f(Wr, isbf, (size_t)j * 128 + (k - 128));
        Wcp[t * 8 + jj] = f2b(v);
    }
}

// ---------------- aggregation: one wave per node, 8-deep MLP ----------------

__global__ void agg_kernel(const u32* __restrict__ F2, const int* __restrict__ offsets,
                           const int* __restrict__ cnt, const float* __restrict__ inv_deg,
                           const int* __restrict__ csr, u32* __restrict__ Aout, int N) {
    int nd = (blockIdx.x * 256 + threadIdx.x) >> 6;
    int lane = threadIdx.x & 63;
    if (nd >= N) return;
    int start = offsets[nd];
    int num = cnt[nd];
    float a0 = 0.f, a1 = 0.f;
    int i = 0;
    for (; i + 8 <= num; i += 8) {
        int s0 = csr[start + i + 0], s1 = csr[start + i + 1];
        int s2 = csr[start + i + 2], s3 = csr[start + i + 3];
        int s4 = csr[start + i + 4], s5 = csr[start + i + 5];
        int s6 = csr[start + i + 6], s7 = csr[start + i + 7];
        u32 u0 = F2[(size_t)s0 * 64 + lane];
        u32 u1 = F2[(size_t)s1 * 64 + lane];
        u32 u2 = F2[(size_t)s2 * 64 + lane];
        u32 u3 = F2[(size_t)s3 * 64 + lane];
        u32 u4 = F2[(size_t)s4 * 64 + lane];
        u32 u5 = F2[(size_t)s5 * 64 + lane];
        u32 u6 = F2[(size_t)s6 * 64 + lane];
        u32 u7 = F2[(size_t)s7 * 64 + lane];
        a0 += lo2f(u0) + lo2f(u1) + lo2f(u2) + lo2f(u3) +
              lo2f(u4) + lo2f(u5) + lo2f(u6) + lo2f(u7);
        a1 += hi2f(u0) + hi2f(u1) + hi2f(u2) + hi2f(u3) +
              hi2f(u4) + hi2f(u5) + hi2f(u6) + hi2f(u7);
    }
    for (; i + 4 <= num; i += 4) {
        int s0 = csr[start + i + 0], s1 = csr[start + i + 1];
        int s2 = csr[start + i + 2], s3 = csr[start + i + 3];
        u32 u0 = F2[(size_t)s0 * 64 + lane];
        u32 u1 = F2[(size_t)s1 * 64 + lane];
        u32 u2 = F2[(size_t)s2 * 64 + lane];
        u32 u3 = F2[(size_t)s3 * 64 + lane];
        a0 += lo2f(u0) + lo2f(u1) + lo2f(u2) + lo2f(u3);
        a1 += hi2f(u0) + hi2f(u1) + hi2f(u2) + hi2f(u3);
    }
    for (; i < num; ++i) {
        u32 u = F2[(size_t)csr[start + i] * 64 + lane];
        a0 += lo2f(u);
        a1 += hi2f(u);
    }
    float sc = inv_deg[nd];
    a0 *= sc;
    a1 *= sc;
    Aout[(size_t)nd * 64 + lane] = (u32)f2b(a0) | ((u32)f2b(a1) << 16);
}

// ---------------- dual-GEMM: F = act(concat(agg,F) @ Wc + b), IN-PLACE ----------------
// block=256 (4 waves) handles 128 nodes. Each wave reads ONLY its own 32 rows
// of Fio before writing them (row-independent MFMA) -> in-place safe; clamped
// tail rows may race but corrupt only discarded (>=N) outputs.
// If outp != nullptr (last layer): fused output head, no Fio store.

__global__ void gemm_kernel(const u32* __restrict__ aggb, u32* Fio,
                            const u16* __restrict__ Wcp, const float* __restrict__ biasf,
                            int N, int relu, const float* __restrict__ headw,
                            const int* __restrict__ flags, void* __restrict__ outp) {
    int tid = threadIdx.x;
    int w = tid >> 6;
    int lane = tid & 63;
    int nbase = blockIdx.x * 128;
    int n = lane & 31;
    int q = lane >> 5;
    int rowl = w * 32 + n;
    int node = nbase + rowl;
    int nodeC = (node < N) ? node : (N - 1);
    const u32* aRow = aggb + (size_t)nodeC * 64 + q * 4;
    const u32* fRow = Fio + (size_t)nodeC * 64 + q * 4;

    floatx16 acc0 = 0.0f, acc1 = 0.0f, acc2 = 0.0f, acc3 = 0.0f;

#pragma unroll
    for (int s = 0; s < 16; ++s) {
        const u32* ap = (s < 8) ? (aRow + (size_t)s * 8) : (fRow + (size_t)(s - 8) * 8);
        bf16x8 a = *reinterpret_cast<const bf16x8*>(ap);
        const u16* bp = Wcp + (size_t)((s * 4) * 64 + lane) * 8;
        bf16x8 b0 = *reinterpret_cast<const bf16x8*>(bp);
        bf16x8 b1 = *reinterpret_cast<const bf16x8*>(bp + 64 * 8);
        bf16x8 b2 = *reinterpret_cast<const bf16x8*>(bp + 2 * 64 * 8);
        bf16x8 b3 = *reinterpret_cast<const bf16x8*>(bp + 3 * 64 * 8);
        acc0 = __builtin_amdgcn_mfma_f32_32x32x16_bf16(a, b0, acc0, 0, 0, 0);
        acc1 = __builtin_amdgcn_mfma_f32_32x32x16_bf16(a, b1, acc1, 0, 0, 0);
        acc2 = __builtin_amdgcn_mfma_f32_32x32x16_bf16(a, b2, acc2, 0, 0, 0);
        acc3 = __builtin_amdgcn_mfma_f32_32x32x16_bf16(a, b3, acc3, 0, 0, 0);
    }

    int mbase = nbase + w * 32;
    floatx16 accs[4] = {acc0, acc1, acc2, acc3};
    // C/D: col=lane&31, row=(r&3)+8*(r>>2)+4*(lane>>5)  [verified m74/m101]

    if (outp == nullptr) {
#pragma unroll
        for (int jt = 0; jt < 4; ++jt) {
            int j0 = jt * 32 + n;
            float bf = biasf[j0];
#pragma unroll
            for (int r = 0; r < 16; ++r) {
                int row = (r & 3) + 8 * (r >> 2) + 4 * q;
                int nodeS = mbase + row;
                if (nodeS < N) {
                    float v = accs[jt][r] + bf;
                    if (relu) v = fmaxf(v, 0.0f);
                    u16* dst16 = (u16*)&Fio[(size_t)nodeS * 64];
                    dst16[j0] = f2b(v);
                }
            }
        }
    } else {
        // fused head: out[node] = (h·Wo0 + bo0, h·Wo1 + bo1); h = acc + bl3
        int isbf = flags[1];
#pragma unroll
        for (int r = 0; r < 16; ++r) {
            float p0 = 0.f, p1 = 0.f;
#pragma unroll
            for (int jt = 0; jt < 4; ++jt) {
                int j = jt * 32 + n;
                float v = accs[jt][r] + biasf[j];
                p0 += v * headw[j];
                p1 += v * headw[128 + j];
            }
#pragma unroll
            for (int off = 16; off > 0; off >>= 1) {
                p0 += __shfl_xor(p0, off);
                p1 += __shfl_xor(p1, off);
            }
            if (n == 0) {
                int row = (r & 3) + 8 * (r >> 2) + 4 * q;
                int nodeS = mbase + row;
                if (nodeS < N) {
                    float o0 = p0 + headw[256];  // bo0
                    float o1 = p1 + headw[257];  // bo1
                    if (isbf)
                        ((u32*)outp)[nodeS] = (u32)f2b(o0) | ((u32)f2b(o1) << 16);
                    else
                        ((float2*)outp)[nodeS] = make_float2(o0, o1);
                }
            }
        }
    }
}

extern "C" void kernel_launch(void* const* d_in, const int* in_sizes, int n_in,
                              void* d_out, int out_size, void* d_ws, size_t ws_size,
                              hipStream_t stream) {
    const int N = in_sizes[0] / 128;
    const int E = in_sizes[1] / 2;

    const void* x = d_in[0];
    const int* ei = (const int*)d_in[1];
    const void* Wl[3] = {d_in[2], d_in[5], d_in[8]};
    const void* bl[3] = {d_in[3], d_in[6], d_in[9]};
    const void* Wr[3] = {d_in[4], d_in[7], d_in[10]};
    const void* Wo = d_in[11];
    const void* bo = d_in[12];

    // workspace bump allocator (256B aligned); total ~57 MB (proven footprint)
    char* p = (char*)d_ws;
    auto alloc = [&](size_t bytes) -> char* {
        char* r = p;
        p += (bytes + 255) & ~(size_t)255;
        return r;
    };
    int* flags = (int*)alloc(256);
    int* cnt = (int*)alloc((size_t)N * 4);
    int* offs = (int*)alloc((size_t)N * 4);
    int* cursor = (int*)alloc((size_t)N * 4);
    float* invd = (float*)alloc((size_t)N * 4);
    int* bsums = (int*)alloc(2048);
    float* smalls = (float*)alloc(642 * 4);
    int* csr = (int*)alloc((size_t)E * 4);
    u16* Wcp = (u16*)alloc((size_t)3 * 4096 * 8 * 2);
    u32* xb = (u32*)alloc((size_t)N * 64 * 4);    // features, updated IN-PLACE per layer
    u32* aggb = (u32*)alloc((size_t)N * 64 * 4);  // aggregated neighbor features
    (void)ws_size;

    const int nb = (N + 255) / 256;
    const int eb = (E + 255) / 256;
    const int wb = (N + 3) / 4;      // wave-per-node kernels
    const int gb = (N + 127) / 128;  // gemm blocks
    const int cb = (N * 16 + 255) / 256;

    detect_kernel<<<1, 64, 0, stream>>>(ei, (const u32*)x, flags);
    hipMemsetAsync(cnt, 0, (size_t)N * 4, stream);
    hist_kernel<<<eb, 256, 0, stream>>>(ei, E, flags, N, cnt);
    scan_blocks_kernel<<<nb, 256, 0, stream>>>(cnt, N, offs, bsums, invd);
    scan_sums_kernel<<<1, 64, 0, stream>>>(bsums, nb);
    finalize_kernel<<<nb, 256, 0, stream>>>(offs, bsums, N, cursor);
    fill_kernel<<<eb, 256, 0, stream>>>(ei, E, flags, N, cursor, csr);

    convert_x_kernel<<<cb, 256, 0, stream>>>(x, flags, xb, N * 16);
    convert_smalls_kernel<<<1, 768, 0, stream>>>(bl[0], bl[1], bl[2], Wo, bo, flags, smalls);
    for (int l = 0; l < 3; ++l)
        wprep_kernel<<<16, 256, 0, stream>>>(Wl[l], Wr[l], flags, Wcp + (size_t)l * 32768);

    // layer 1
    agg_kernel<<<wb, 256, 0, stream>>>(xb, offs, cnt, invd, csr, aggb, N);
    gemm_kernel<<<gb, 256, 0, stream>>>(aggb, xb, Wcp, smalls, N, 1, nullptr, flags, nullptr);
    // layer 2
    agg_kernel<<<wb, 256, 0, stream>>>(xb, offs, cnt, invd, csr, aggb, N);
    gemm_kernel<<<gb, 256, 0, stream>>>(aggb, xb, Wcp + 32768, smalls + 128, N, 1, nullptr, flags, nullptr);
    // layer 3 + fused head
    agg_kernel<<<wb, 256, 0, stream>>>(xb, offs, cnt, invd, csr, aggb, N);
    gemm_kernel<<<gb, 256, 0, stream>>>(aggb, xb, Wcp + 65536, smalls + 256, N, 0,
                                        smalls + 384, flags, d_out);
}

// Round 6
// 371.181 us; speedup vs baseline: 2.2342x; 1.1983x over previous
//
#include <hip/hip_runtime.h>
#include <stdint.h>

typedef unsigned int u32;
typedef unsigned short u16;
typedef __bf16 bf16x8 __attribute__((ext_vector_type(8)));
typedef float floatx16 __attribute__((ext_vector_type(16)));
typedef u32 u32x4 __attribute__((ext_vector_type(4)));
typedef float floatx4 __attribute__((ext_vector_type(4)));

__device__ __forceinline__ u16 f2b(float f) {
    u32 u = __builtin_bit_cast(u32, f);
    u32 r = u + 0x7FFFu + ((u >> 16) & 1u);
    return (u16)(r >> 16);
}
__device__ __forceinline__ float lo2f(u32 u) { return __builtin_bit_cast(float, u << 16); }
__device__ __forceinline__ float hi2f(u32 u) { return __builtin_bit_cast(float, u & 0xFFFF0000u); }

// ---------------- runtime dtype detection + bucket-hist zero ----------------
// flags[0] = edge_index is int64; flags[1] = floats are bf16

__global__ void detect_kernel(const int* __restrict__ ei, const u32* __restrict__ xw,
                              int* __restrict__ flags, int* __restrict__ ghist) {
    int t = threadIdx.x;  // 1024
    ghist[t] = 0;
    if (t < 64) {
        int v = ei[2 * t + 1];
        unsigned long long b1 = __ballot(v == 0);
        u32 w = xw[t];
        u32 e = (w >> 7) & 0xFF;
        int plaus = (e == 0) || (e >= 90 && e <= 140);
        unsigned long long b2 = __ballot(plaus);
        if (t == 0) {
            flags[0] = (b1 == ~0ULL) ? 1 : 0;
            flags[1] = (b2 == ~0ULL) ? 1 : 0;
        }
    }
}

__device__ __forceinline__ int load_id(const int* __restrict__ ei, int is64, size_t pos, int N) {
    int v = is64 ? ei[2 * pos] : ei[pos];
    unsigned u = (unsigned)v;
    if (u >= (unsigned)N) u = 0;  // clamp: never OOB
    return (int)u;
}

__device__ __forceinline__ float load_f(const void* __restrict__ p, int isbf, size_t i) {
    if (isbf) {
        u16 s = ((const u16*)p)[i];
        return __builtin_bit_cast(float, ((u32)s) << 16);
    }
    return ((const float*)p)[i];
}

// ---------------- conversion front-end ----------------

__global__ void convert_x_kernel(const void* __restrict__ xraw, const int* __restrict__ flags,
                                 u32* __restrict__ xb, int count4) {
    int i = blockIdx.x * 256 + threadIdx.x;
    if (i >= count4) return;
    if (flags[1]) {
        ((u32x4*)xb)[i] = ((const u32x4*)xraw)[i];
    } else {
        const floatx4* f4 = (const floatx4*)xraw;
        floatx4 f0 = f4[2 * i], f1 = f4[2 * i + 1];
        u32x4 o;
        o.x = (u32)f2b(f0.x) | ((u32)f2b(f0.y) << 16);
        o.y = (u32)f2b(f0.z) | ((u32)f2b(f0.w) << 16);
        o.z = (u32)f2b(f1.x) | ((u32)f2b(f1.y) << 16);
        o.w = (u32)f2b(f1.z) | ((u32)f2b(f1.w) << 16);
        ((u32x4*)xb)[i] = o;
    }
}

// fp32 smalls: [0,384) bl1|bl2|bl3, [384,640) Wo, [640,642) bo
__global__ void convert_smalls_kernel(const void* b0, const void* b1, const void* b2,
                                      const void* Wo, const void* bo,
                                      const int* __restrict__ flags, float* __restrict__ out) {
    int t = threadIdx.x;  // one block of 768
    int isbf = flags[1];
    if (t < 128) out[t] = load_f(b0, isbf, t);
    else if (t < 256) out[t] = load_f(b1, isbf, t - 128);
    else if (t < 384) out[t] = load_f(b2, isbf, t - 256);
    else if (t < 640) out[t] = load_f(Wo, isbf, t - 384);
    else if (t < 642) out[t] = load_f(bo, isbf, t - 640);
}

// ---------------- bucketed CSR build (all global writes coalesced) ----------------
// bucket = dst >> 8 (256 nodes per bucket). Assumes N <= 2^18 (buckets <= 1024)
// and N < 2^24 (src packs in 24 bits) — holds for this problem (N = 100k).

__global__ void bucket_hist_kernel(const int* __restrict__ ei, int E,
                                   const int* __restrict__ flags, int N,
                                   int* __restrict__ ghist) {
    __shared__ int lh[1024];
    int t = threadIdx.x;  // 256
    for (int i = t; i < 1024; i += 256) lh[i] = 0;
    __syncthreads();
    int is64 = flags[0];
    for (int e = blockIdx.x * 256 + t; e < E; e += gridDim.x * 256) {
        int d = load_id(ei, is64, (size_t)E + e, N);
        atomicAdd(&lh[d >> 8], 1);
    }
    __syncthreads();
    for (int i = t; i < 1024; i += 256)
        if (lh[i]) atomicAdd(&ghist[i], lh[i]);
}

__global__ void bucket_scan_kernel(const int* __restrict__ ghist, int* __restrict__ bbase,
                                   int* __restrict__ gcur) {
    __shared__ int wsum[16];
    int t = threadIdx.x;  // 1024
    int lane = t & 63, wid = t >> 6;
    int v = ghist[t];
    int inc = v;
#pragma unroll
    for (int off = 1; off < 64; off <<= 1) {
        int o = __shfl_up(inc, off);
        if (lane >= off) inc += o;
    }
    if (lane == 63) wsum[wid] = inc;
    __syncthreads();
    int wpre = 0;
    for (int w = 0; w < wid; ++w) wpre += wsum[w];
    int excl = wpre + inc - v;
    bbase[t] = excl;
    gcur[t] = excl;
}

#define CH 4096

__global__ void bucket_scatter_kernel(const int* __restrict__ ei, int E,
                                      const int* __restrict__ flags, int N,
                                      int* __restrict__ gcur, u32* __restrict__ csrbkt) {
    __shared__ int lhist[1024], loff[1024], lcur[1024], gbase[1024], wsum[16];
    __shared__ u32 ebuf[CH];
    __shared__ u16 ebkt[CH];
    int t = threadIdx.x;  // 1024
    int cbase = blockIdx.x * CH;
    int cn = E - cbase;
    if (cn > CH) cn = CH;
    lhist[t] = 0;
    __syncthreads();
    int is64 = flags[0];
    int mysrc[4], myb[4], mydl[4];
#pragma unroll
    for (int k = 0; k < 4; ++k) {
        int i = t + k * 1024;
        myb[k] = -1;
        if (i < cn) {
            int e = cbase + i;
            int s = load_id(ei, is64, (size_t)e, N);
            int d = load_id(ei, is64, (size_t)E + e, N);
            mysrc[k] = s;
            mydl[k] = d & 255;
            myb[k] = d >> 8;
            atomicAdd(&lhist[myb[k]], 1);
        }
    }
    __syncthreads();
    // block scan over 1024 bucket counts
    int lane = t & 63, wid = t >> 6;
    int v = lhist[t];
    int inc = v;
#pragma unroll
    for (int off = 1; off < 64; off <<= 1) {
        int o = __shfl_up(inc, off);
        if (lane >= off) inc += o;
    }
    if (lane == 63) wsum[wid] = inc;
    __syncthreads();
    int wpre = 0;
    for (int w = 0; w < wid; ++w) wpre += wsum[w];
    int excl = wpre + inc - v;
    loff[t] = excl;
    lcur[t] = excl;
    if (v > 0) gbase[t] = atomicAdd(&gcur[t], v);
    __syncthreads();
    // LDS scatter: group this chunk's edges by bucket
#pragma unroll
    for (int k = 0; k < 4; ++k) {
        if (myb[k] >= 0) {
            int pos = atomicAdd(&lcur[myb[k]], 1);
            ebuf[pos] = (u32)mysrc[k] | ((u32)mydl[k] << 24);
            ebkt[pos] = (u16)myb[k];
        }
    }
    __syncthreads();
    // write runs: consecutive i within a bucket -> consecutive global slots
#pragma unroll
    for (int k = 0; k < 4; ++k) {
        int i = t + k * 1024;
        if (i < cn) {
            int bb = ebkt[i];
            csrbkt[gbase[bb] + (i - loff[bb])] = ebuf[i];
        }
    }
}

#define CAP3 8192

__global__ void csr_build_kernel(const u32* __restrict__ csrbkt, const int* __restrict__ ghist,
                                 const int* __restrict__ bbase, int N,
                                 int* __restrict__ offs, int* __restrict__ cnt,
                                 float* __restrict__ invd, int* __restrict__ csr) {
    __shared__ int lh[256], lo[256], lcur[256], wsum[4];
    __shared__ u32 sbuf[CAP3];
    int t = threadIdx.x;  // 256
    int b = blockIdx.x;
    int base = bbase[b];
    int cb = ghist[b];
    int d0 = b << 8;
    lh[t] = 0;
    __syncthreads();
    for (int i = t; i < cb; i += 256) atomicAdd(&lh[csrbkt[base + i] >> 24], 1);
    __syncthreads();
    int lane = t & 63, wid = t >> 6;
    int v = lh[t];
    int inc = v;
#pragma unroll
    for (int off = 1; off < 64; off <<= 1) {
        int o = __shfl_up(inc, off);
        if (lane >= off) inc += o;
    }
    if (lane == 63) wsum[wid] = inc;
    __syncthreads();
    int wpre = 0;
    for (int w = 0; w < wid; ++w) wpre += wsum[w];
    int excl = wpre + inc - v;
    lo[t] = excl;
    lcur[t] = excl;
    int d = d0 + t;
    if (d < N) {
        offs[d] = base + excl;
        cnt[d] = v;
        invd[d] = 1.0f / (float)(v > 1 ? v : 1);
    }
    __syncthreads();
    if (cb <= CAP3) {
        for (int i = t; i < cb; i += 256) {
            u32 e = csrbkt[base + i];
            int pos = atomicAdd(&lcur[e >> 24], 1);
            sbuf[pos] = e & 0xFFFFFFu;
        }
        __syncthreads();
        for (int i = t; i < cb; i += 256) csr[base + i] = (int)sbuf[i];
    } else {
        // emergency fallback (never for uniform random): thread t owns dst-low t
        int c = base + lo[t];
        for (int i = 0; i < cb; ++i) {
            u32 e = csrbkt[base + i];
            if ((int)(e >> 24) == t) csr[c++] = (int)(e & 0xFFFFFFu);
        }
    }
}

// ---------------- weight swizzle (B-fragment order, bf16 out) ----------------

__global__ void wprep_kernel(const void* __restrict__ Wl, const void* __restrict__ Wr,
                             const int* __restrict__ flags, u16* __restrict__ Wcp) {
    int t = blockIdx.x * 256 + threadIdx.x;  // 0..4095
    int isbf = flags[1];
    int lane = t & 63;
    int jt = (t >> 6) & 3;
    int s = t >> 8;
    int n = lane & 31;
    int q = lane >> 5;
    int j = jt * 32 + n;
#pragma unroll
    for (int jj = 0; jj < 8; ++jj) {
        int k = s * 16 + q * 8 + jj;
        float v = (k < 128) ? load_f(Wl, isbf, (size_t)j * 128 + k)
                            : load_f(Wr, isbf, (size_t)j * 128 + (k - 128));
        Wcp[t * 8 + jj] = f2b(v);
    }
}

// ---------------- aggregation: one wave per node, 8-deep MLP ----------------

__global__ void agg_kernel(const u32* __restrict__ F2, const int* __restrict__ offsets,
                           const int* __restrict__ cnt, const float* __restrict__ inv_deg,
                           const int* __restrict__ csr, u32* __restrict__ Aout, int N) {
    int nd = (blockIdx.x * 256 + threadIdx.x) >> 6;
    int lane = threadIdx.x & 63;
    if (nd >= N) return;
    int start = offsets[nd];
    int num = cnt[nd];
    float a0 = 0.f, a1 = 0.f;
    int i = 0;
    for (; i + 8 <= num; i += 8) {
        int s0 = csr[start + i + 0], s1 = csr[start + i + 1];
        int s2 = csr[start + i + 2], s3 = csr[start + i + 3];
        int s4 = csr[start + i + 4], s5 = csr[start + i + 5];
        int s6 = csr[start + i + 6], s7 = csr[start + i + 7];
        u32 u0 = F2[(size_t)s0 * 64 + lane];
        u32 u1 = F2[(size_t)s1 * 64 + lane];
        u32 u2 = F2[(size_t)s2 * 64 + lane];
        u32 u3 = F2[(size_t)s3 * 64 + lane];
        u32 u4 = F2[(size_t)s4 * 64 + lane];
        u32 u5 = F2[(size_t)s5 * 64 + lane];
        u32 u6 = F2[(size_t)s6 * 64 + lane];
        u32 u7 = F2[(size_t)s7 * 64 + lane];
        a0 += lo2f(u0) + lo2f(u1) + lo2f(u2) + lo2f(u3) +
              lo2f(u4) + lo2f(u5) + lo2f(u6) + lo2f(u7);
        a1 += hi2f(u0) + hi2f(u1) + hi2f(u2) + hi2f(u3) +
              hi2f(u4) + hi2f(u5) + hi2f(u6) + hi2f(u7);
    }
    for (; i + 4 <= num; i += 4) {
        int s0 = csr[start + i + 0], s1 = csr[start + i + 1];
        int s2 = csr[start + i + 2], s3 = csr[start + i + 3];
        u32 u0 = F2[(size_t)s0 * 64 + lane];
        u32 u1 = F2[(size_t)s1 * 64 + lane];
        u32 u2 = F2[(size_t)s2 * 64 + lane];
        u32 u3 = F2[(size_t)s3 * 64 + lane];
        a0 += lo2f(u0) + lo2f(u1) + lo2f(u2) + lo2f(u3);
        a1 += hi2f(u0) + hi2f(u1) + hi2f(u2) + hi2f(u3);
    }
    for (; i < num; ++i) {
        u32 u = F2[(size_t)csr[start + i] * 64 + lane];
        a0 += lo2f(u);
        a1 += hi2f(u);
    }
    float sc = inv_deg[nd];
    a0 *= sc;
    a1 *= sc;
    Aout[(size_t)nd * 64 + lane] = (u32)f2b(a0) | ((u32)f2b(a1) << 16);
}

// ---------------- dual-GEMM: F = act(concat(agg,F) @ Wc + b), IN-PLACE ----------------

__global__ void gemm_kernel(const u32* __restrict__ aggb, u32* Fio,
                            const u16* __restrict__ Wcp, const float* __restrict__ biasf,
                            int N, int relu, const float* __restrict__ headw,
                            const int* __restrict__ flags, void* __restrict__ outp) {
    int tid = threadIdx.x;
    int w = tid >> 6;
    int lane = tid & 63;
    int nbase = blockIdx.x * 128;
    int n = lane & 31;
    int q = lane >> 5;
    int rowl = w * 32 + n;
    int node = nbase + rowl;
    int nodeC = (node < N) ? node : (N - 1);
    const u32* aRow = aggb + (size_t)nodeC * 64 + q * 4;
    const u32* fRow = Fio + (size_t)nodeC * 64 + q * 4;

    floatx16 acc0 = 0.0f, acc1 = 0.0f, acc2 = 0.0f, acc3 = 0.0f;

#pragma unroll
    for (int s = 0; s < 16; ++s) {
        const u32* ap = (s < 8) ? (aRow + (size_t)s * 8) : (fRow + (size_t)(s - 8) * 8);
        bf16x8 a = *reinterpret_cast<const bf16x8*>(ap);
        const u16* bp = Wcp + (size_t)((s * 4) * 64 + lane) * 8;
        bf16x8 b0 = *reinterpret_cast<const bf16x8*>(bp);
        bf16x8 b1 = *reinterpret_cast<const bf16x8*>(bp + 64 * 8);
        bf16x8 b2 = *reinterpret_cast<const bf16x8*>(bp + 2 * 64 * 8);
        bf16x8 b3 = *reinterpret_cast<const bf16x8*>(bp + 3 * 64 * 8);
        acc0 = __builtin_amdgcn_mfma_f32_32x32x16_bf16(a, b0, acc0, 0, 0, 0);
        acc1 = __builtin_amdgcn_mfma_f32_32x32x16_bf16(a, b1, acc1, 0, 0, 0);
        acc2 = __builtin_amdgcn_mfma_f32_32x32x16_bf16(a, b2, acc2, 0, 0, 0);
        acc3 = __builtin_amdgcn_mfma_f32_32x32x16_bf16(a, b3, acc3, 0, 0, 0);
    }

    int mbase = nbase + w * 32;
    floatx16 accs[4] = {acc0, acc1, acc2, acc3};
    // C/D: col=lane&31, row=(r&3)+8*(r>>2)+4*(lane>>5)  [verified m74/m101]

    if (outp == nullptr) {
#pragma unroll
        for (int jt = 0; jt < 4; ++jt) {
            int j0 = jt * 32 + n;
            float bf = biasf[j0];
#pragma unroll
            for (int r = 0; r < 16; ++r) {
                int row = (r & 3) + 8 * (r >> 2) + 4 * q;
                int nodeS = mbase + row;
                if (nodeS < N) {
                    float v = accs[jt][r] + bf;
                    if (relu) v = fmaxf(v, 0.0f);
                    u16* dst16 = (u16*)&Fio[(size_t)nodeS * 64];
                    dst16[j0] = f2b(v);
                }
            }
        }
    } else {
        // fused head: out[node] = (h·Wo0 + bo0, h·Wo1 + bo1); h = acc + bl3
        int isbf = flags[1];
#pragma unroll
        for (int r = 0; r < 16; ++r) {
            float p0 = 0.f, p1 = 0.f;
#pragma unroll
            for (int jt = 0; jt < 4; ++jt) {
                int j = jt * 32 + n;
                float v = accs[jt][r] + biasf[j];
                p0 += v * headw[j];
                p1 += v * headw[128 + j];
            }
#pragma unroll
            for (int off = 16; off > 0; off >>= 1) {
                p0 += __shfl_xor(p0, off);
                p1 += __shfl_xor(p1, off);
            }
            if (n == 0) {
                int row = (r & 3) + 8 * (r >> 2) + 4 * q;
                int nodeS = mbase + row;
                if (nodeS < N) {
                    float o0 = p0 + headw[256];  // bo0
                    float o1 = p1 + headw[257];  // bo1
                    if (isbf)
                        ((u32*)outp)[nodeS] = (u32)f2b(o0) | ((u32)f2b(o1) << 16);
                    else
                        ((float2*)outp)[nodeS] = make_float2(o0, o1);
                }
            }
        }
    }
}

extern "C" void kernel_launch(void* const* d_in, const int* in_sizes, int n_in,
                              void* d_out, int out_size, void* d_ws, size_t ws_size,
                              hipStream_t stream) {
    const int N = in_sizes[0] / 128;
    const int E = in_sizes[1] / 2;

    const void* x = d_in[0];
    const int* ei = (const int*)d_in[1];
    const void* Wl[3] = {d_in[2], d_in[5], d_in[8]};
    const void* bl[3] = {d_in[3], d_in[6], d_in[9]};
    const void* Wr[3] = {d_in[4], d_in[7], d_in[10]};
    const void* Wo = d_in[11];
    const void* bo = d_in[12];

    // workspace bump allocator (256B aligned); ~57 MB (proven footprint)
    char* p = (char*)d_ws;
    auto alloc = [&](size_t bytes) -> char* {
        char* r = p;
        p += (bytes + 255) & ~(size_t)255;
        return r;
    };
    int* flags = (int*)alloc(256);
    int* cnt = (int*)alloc((size_t)N * 4);
    int* offs = (int*)alloc((size_t)N * 4);
    float* invd = (float*)alloc((size_t)N * 4);
    float* smalls = (float*)alloc(642 * 4);
    int* ghist = (int*)alloc(1024 * 4);
    int* bbase = (int*)alloc(1024 * 4);
    int* gcur = (int*)alloc(1024 * 4);
    int* csr = (int*)alloc((size_t)E * 4);
    u16* Wcp = (u16*)alloc((size_t)3 * 4096 * 8 * 2);
    u32* xb = (u32*)alloc((size_t)N * 64 * 4);    // features, updated IN-PLACE per layer
    u32* aggb = (u32*)alloc((size_t)N * 64 * 4);  // agg features; aliased as csrbkt during build
    u32* csrbkt = aggb;                            // dead until layers start
    (void)ws_size;

    const int NB = (N + 255) / 256;  // buckets
    const int wb = (N + 3) / 4;      // wave-per-node kernels
    const int gb = (N + 127) / 128;  // gemm blocks
    const int cb = (N * 16 + 255) / 256;
    const int sb = (E + CH - 1) / CH;

    detect_kernel<<<1, 1024, 0, stream>>>(ei, (const u32*)x, flags, ghist);
    bucket_hist_kernel<<<256, 256, 0, stream>>>(ei, E, flags, N, ghist);
    bucket_scan_kernel<<<1, 1024, 0, stream>>>(ghist, bbase, gcur);
    bucket_scatter_kernel<<<sb, 1024, 0, stream>>>(ei, E, flags, N, gcur, csrbkt);
    csr_build_kernel<<<NB, 256, 0, stream>>>(csrbkt, ghist, bbase, N, offs, cnt, invd, csr);

    convert_x_kernel<<<cb, 256, 0, stream>>>(x, flags, xb, N * 16);
    convert_smalls_kernel<<<1, 768, 0, stream>>>(bl[0], bl[1], bl[2], Wo, bo, flags, smalls);
    for (int l = 0; l < 3; ++l)
        wprep_kernel<<<16, 256, 0, stream>>>(Wl[l], Wr[l], flags, Wcp + (size_t)l * 32768);

    // layer 1
    agg_kernel<<<wb, 256, 0, stream>>>(xb, offs, cnt, invd, csr, aggb, N);
    gemm_kernel<<<gb, 256, 0, stream>>>(aggb, xb, Wcp, smalls, N, 1, nullptr, flags, nullptr);
    // layer 2
    agg_kernel<<<wb, 256, 0, stream>>>(xb, offs, cnt, invd, csr, aggb, N);
    gemm_kernel<<<gb, 256, 0, stream>>>(aggb, xb, Wcp + 32768, smalls + 128, N, 1, nullptr, flags, nullptr);
    // layer 3 + fused head
    agg_kernel<<<wb, 256, 0, stream>>>(xb, offs, cnt, invd, csr, aggb, N);
    gemm_kernel<<<gb, 256, 0, stream>>>(aggb, xb, Wcp + 65536, smalls + 256, N, 0,
                                        smalls + 384, flags, d_out);
}

// Round 7
// 350.486 us; speedup vs baseline: 2.3661x; 1.0590x over previous
//
#include <hip/hip_runtime.h>
#include <stdint.h>

typedef unsigned int u32;
typedef unsigned short u16;
typedef __bf16 bf16x8 __attribute__((ext_vector_type(8)));
typedef float floatx16 __attribute__((ext_vector_type(16)));
typedef u32 u32x4 __attribute__((ext_vector_type(4)));
typedef float floatx4 __attribute__((ext_vector_type(4)));

__device__ __forceinline__ u16 f2b(float f) {
    u32 u = __builtin_bit_cast(u32, f);
    u32 r = u + 0x7FFFu + ((u >> 16) & 1u);
    return (u16)(r >> 16);
}
__device__ __forceinline__ float lo2f(u32 u) { return __builtin_bit_cast(float, u << 16); }
__device__ __forceinline__ float hi2f(u32 u) { return __builtin_bit_cast(float, u & 0xFFFF0000u); }

// ---------------- runtime dtype detection + bucket-hist zero ----------------
// flags[0] = edge_index is int64; flags[1] = floats are bf16

__global__ void detect_kernel(const int* __restrict__ ei, const u32* __restrict__ xw,
                              int* __restrict__ flags, int* __restrict__ ghist) {
    int t = threadIdx.x;  // 1024
    ghist[t] = 0;
    if (t < 64) {
        int v = ei[2 * t + 1];
        unsigned long long b1 = __ballot(v == 0);
        u32 w = xw[t];
        u32 e = (w >> 7) & 0xFF;
        int plaus = (e == 0) || (e >= 90 && e <= 140);
        unsigned long long b2 = __ballot(plaus);
        if (t == 0) {
            flags[0] = (b1 == ~0ULL) ? 1 : 0;
            flags[1] = (b2 == ~0ULL) ? 1 : 0;
        }
    }
}

__device__ __forceinline__ int load_id(const int* __restrict__ ei, int is64, size_t pos, int N) {
    int v = is64 ? ei[2 * pos] : ei[pos];
    unsigned u = (unsigned)v;
    if (u >= (unsigned)N) u = 0;  // clamp: never OOB
    return (int)u;
}

__device__ __forceinline__ float load_f(const void* __restrict__ p, int isbf, size_t i) {
    if (isbf) {
        u16 s = ((const u16*)p)[i];
        return __builtin_bit_cast(float, ((u32)s) << 16);
    }
    return ((const float*)p)[i];
}

// ---------------- conversion front-end ----------------

__global__ void convert_x_kernel(const void* __restrict__ xraw, const int* __restrict__ flags,
                                 u32* __restrict__ xb, int count4) {
    int i = blockIdx.x * 256 + threadIdx.x;
    if (i >= count4) return;
    if (flags[1]) {
        ((u32x4*)xb)[i] = ((const u32x4*)xraw)[i];
    } else {
        const floatx4* f4 = (const floatx4*)xraw;
        floatx4 f0 = f4[2 * i], f1 = f4[2 * i + 1];
        u32x4 o;
        o.x = (u32)f2b(f0.x) | ((u32)f2b(f0.y) << 16);
        o.y = (u32)f2b(f0.z) | ((u32)f2b(f0.w) << 16);
        o.z = (u32)f2b(f1.x) | ((u32)f2b(f1.y) << 16);
        o.w = (u32)f2b(f1.z) | ((u32)f2b(f1.w) << 16);
        ((u32x4*)xb)[i] = o;
    }
}

// ---------------- bucketed CSR build (all global writes coalesced) ----------------
// bucket = dst >> 8. Assumes N <= 2^18 and N < 2^24 (holds: N = 100k).

__global__ void bucket_hist_kernel(const int* __restrict__ ei, int E,
                                   const int* __restrict__ flags, int N,
                                   int* __restrict__ ghist) {
    __shared__ int lh[1024];
    int t = threadIdx.x;  // 256
    for (int i = t; i < 1024; i += 256) lh[i] = 0;
    __syncthreads();
    int is64 = flags[0];
    for (int e = blockIdx.x * 256 + t; e < E; e += gridDim.x * 256) {
        int d = load_id(ei, is64, (size_t)E + e, N);
        atomicAdd(&lh[d >> 8], 1);
    }
    __syncthreads();
    for (int i = t; i < 1024; i += 256)
        if (lh[i]) atomicAdd(&ghist[i], lh[i]);
}

__global__ void bucket_scan_kernel(const int* __restrict__ ghist, int* __restrict__ bbase,
                                   int* __restrict__ gcur) {
    __shared__ int wsum[16];
    int t = threadIdx.x;  // 1024
    int lane = t & 63, wid = t >> 6;
    int v = ghist[t];
    int inc = v;
#pragma unroll
    for (int off = 1; off < 64; off <<= 1) {
        int o = __shfl_up(inc, off);
        if (lane >= off) inc += o;
    }
    if (lane == 63) wsum[wid] = inc;
    __syncthreads();
    int wpre = 0;
    for (int w = 0; w < wid; ++w) wpre += wsum[w];
    int excl = wpre + inc - v;
    bbase[t] = excl;
    gcur[t] = excl;
}

#define CH 4096

__global__ void bucket_scatter_kernel(const int* __restrict__ ei, int E,
                                      const int* __restrict__ flags, int N,
                                      int* __restrict__ gcur, u32* __restrict__ csrbkt) {
    __shared__ int lhist[1024], loff[1024], lcur[1024], gbase[1024], wsum[16];
    __shared__ u32 ebuf[CH];
    __shared__ u16 ebkt[CH];
    int t = threadIdx.x;  // 1024
    int cbase = blockIdx.x * CH;
    int cn = E - cbase;
    if (cn > CH) cn = CH;
    lhist[t] = 0;
    __syncthreads();
    int is64 = flags[0];
    int mysrc[4], myb[4], mydl[4];
#pragma unroll
    for (int k = 0; k < 4; ++k) {
        int i = t + k * 1024;
        myb[k] = -1;
        if (i < cn) {
            int e = cbase + i;
            int s = load_id(ei, is64, (size_t)e, N);
            int d = load_id(ei, is64, (size_t)E + e, N);
            mysrc[k] = s;
            mydl[k] = d & 255;
            myb[k] = d >> 8;
            atomicAdd(&lhist[myb[k]], 1);
        }
    }
    __syncthreads();
    int lane = t & 63, wid = t >> 6;
    int v = lhist[t];
    int inc = v;
#pragma unroll
    for (int off = 1; off < 64; off <<= 1) {
        int o = __shfl_up(inc, off);
        if (lane >= off) inc += o;
    }
    if (lane == 63) wsum[wid] = inc;
    __syncthreads();
    int wpre = 0;
    for (int w = 0; w < wid; ++w) wpre += wsum[w];
    int excl = wpre + inc - v;
    loff[t] = excl;
    lcur[t] = excl;
    if (v > 0) gbase[t] = atomicAdd(&gcur[t], v);
    __syncthreads();
#pragma unroll
    for (int k = 0; k < 4; ++k) {
        if (myb[k] >= 0) {
            int pos = atomicAdd(&lcur[myb[k]], 1);
            ebuf[pos] = (u32)mysrc[k] | ((u32)mydl[k] << 24);
            ebkt[pos] = (u16)myb[k];
        }
    }
    __syncthreads();
#pragma unroll
    for (int k = 0; k < 4; ++k) {
        int i = t + k * 1024;
        if (i < cn) {
            int bb = ebkt[i];
            csrbkt[gbase[bb] + (i - loff[bb])] = ebuf[i];
        }
    }
}

#define CAP3 8192

__global__ void csr_build_kernel(const u32* __restrict__ csrbkt, const int* __restrict__ ghist,
                                 const int* __restrict__ bbase, int N, int E,
                                 int* __restrict__ offs, int* __restrict__ csr) {
    __shared__ int lh[256], lo[256], lcur[256], wsum[4];
    __shared__ u32 sbuf[CAP3];
    int t = threadIdx.x;  // 256
    int b = blockIdx.x;
    int base = bbase[b];
    int cb = ghist[b];
    int d0 = b << 8;
    lh[t] = 0;
    if (b == 0 && t == 0) offs[N] = E;  // sentinel for degree = offs[i+1]-offs[i]
    __syncthreads();
    for (int i = t; i < cb; i += 256) atomicAdd(&lh[csrbkt[base + i] >> 24], 1);
    __syncthreads();
    int lane = t & 63, wid = t >> 6;
    int v = lh[t];
    int inc = v;
#pragma unroll
    for (int off = 1; off < 64; off <<= 1) {
        int o = __shfl_up(inc, off);
        if (lane >= off) inc += o;
    }
    if (lane == 63) wsum[wid] = inc;
    __syncthreads();
    int wpre = 0;
    for (int w = 0; w < wid; ++w) wpre += wsum[w];
    int excl = wpre + inc - v;
    lo[t] = excl;
    lcur[t] = excl;
    int d = d0 + t;
    if (d < N) offs[d] = base + excl;
    __syncthreads();
    if (cb <= CAP3) {
        for (int i = t; i < cb; i += 256) {
            u32 e = csrbkt[base + i];
            int pos = atomicAdd(&lcur[e >> 24], 1);
            sbuf[pos] = e & 0xFFFFFFu;
        }
        __syncthreads();
        for (int i = t; i < cb; i += 256) csr[base + i] = (int)sbuf[i];
    } else {
        // emergency fallback (never for uniform random): thread t owns dst-low t
        int c = base + lo[t];
        for (int i = 0; i < cb; ++i) {
            u32 e = csrbkt[base + i];
            if ((int)(e >> 24) == t) csr[c++] = (int)(e & 0xFFFFFFu);
        }
    }
}

// ---------------- merged prep: weight swizzle (blocks 0..47) + smalls (block 48) ----------------
// Wcp chunk t in [0,4096) per layer: lane=t&63, jt=(t>>6)&3, s=t>>8 holds
// B[k = s*16 + (lane>>5)*8 + jj][j = jt*32 + (lane&31)], jj=0..7
// B[k][j] = (k<128) ? Wl[j][k] : Wr[j][k-128]
// smalls: [0,384) bl1|bl2|bl3, [384,640) Wo, [640,642) bo  (fp32)

__global__ void prep_kernel(const void* Wl1, const void* Wr1, const void* Wl2, const void* Wr2,
                            const void* Wl3, const void* Wr3, const void* b1, const void* b2,
                            const void* b3, const void* Wo, const void* bo,
                            const int* __restrict__ flags, u16* __restrict__ Wcp,
                            float* __restrict__ smalls) {
    int isbf = flags[1];
    int blk = blockIdx.x;
    if (blk < 48) {
        int l = blk >> 4;
        const void* Wl = (l == 0) ? Wl1 : (l == 1) ? Wl2 : Wl3;
        const void* Wr = (l == 0) ? Wr1 : (l == 1) ? Wr2 : Wr3;
        u16* Wout = Wcp + (size_t)l * 32768;
        int t = (blk & 15) * 256 + threadIdx.x;  // 0..4095
        int lane = t & 63;
        int jt = (t >> 6) & 3;
        int s = t >> 8;
        int n = lane & 31;
        int q = lane >> 5;
        int j = jt * 32 + n;
#pragma unroll
        for (int jj = 0; jj < 8; ++jj) {
            int k = s * 16 + q * 8 + jj;
            float v = (k < 128) ? load_f(Wl, isbf, (size_t)j * 128 + k)
                                : load_f(Wr, isbf, (size_t)j * 128 + (k - 128));
            Wout[t * 8 + jj] = f2b(v);
        }
    } else {
        for (int t = threadIdx.x; t < 642; t += 256) {
            float v;
            if (t < 128) v = load_f(b1, isbf, t);
            else if (t < 256) v = load_f(b2, isbf, t - 128);
            else if (t < 384) v = load_f(b3, isbf, t - 256);
            else if (t < 640) v = load_f(Wo, isbf, t - 384);
            else v = load_f(bo, isbf, t - 640);
            smalls[t] = v;
        }
    }
}

// ---------------- aggregation: 4 nodes per wave, 8-deep MLP ----------------

__global__ void agg_kernel(const u32* __restrict__ F2, const int* __restrict__ offs,
                           const int* __restrict__ csr, u32* __restrict__ Aout, int N) {
    int gw = (blockIdx.x * 256 + threadIdx.x) >> 6;  // wave id
    int lane = threadIdx.x & 63;
    int nd0 = gw * 4;
    if (nd0 >= N) return;
    int nd1 = nd0 + 4 < N ? nd0 + 4 : N;
    for (int nd = nd0; nd < nd1; ++nd) {
        int start = offs[nd];
        int num = offs[nd + 1] - start;
        float a0 = 0.f, a1 = 0.f;
        int i = 0;
        for (; i + 8 <= num; i += 8) {
            int s0 = csr[start + i + 0], s1 = csr[start + i + 1];
            int s2 = csr[start + i + 2], s3 = csr[start + i + 3];
            int s4 = csr[start + i + 4], s5 = csr[start + i + 5];
            int s6 = csr[start + i + 6], s7 = csr[start + i + 7];
            u32 u0 = F2[(size_t)s0 * 64 + lane];
            u32 u1 = F2[(size_t)s1 * 64 + lane];
            u32 u2 = F2[(size_t)s2 * 64 + lane];
            u32 u3 = F2[(size_t)s3 * 64 + lane];
            u32 u4 = F2[(size_t)s4 * 64 + lane];
            u32 u5 = F2[(size_t)s5 * 64 + lane];
            u32 u6 = F2[(size_t)s6 * 64 + lane];
            u32 u7 = F2[(size_t)s7 * 64 + lane];
            a0 += lo2f(u0) + lo2f(u1) + lo2f(u2) + lo2f(u3) +
                  lo2f(u4) + lo2f(u5) + lo2f(u6) + lo2f(u7);
            a1 += hi2f(u0) + hi2f(u1) + hi2f(u2) + hi2f(u3) +
                  hi2f(u4) + hi2f(u5) + hi2f(u6) + hi2f(u7);
        }
        for (; i + 4 <= num; i += 4) {
            int s0 = csr[start + i + 0], s1 = csr[start + i + 1];
            int s2 = csr[start + i + 2], s3 = csr[start + i + 3];
            u32 u0 = F2[(size_t)s0 * 64 + lane];
            u32 u1 = F2[(size_t)s1 * 64 + lane];
            u32 u2 = F2[(size_t)s2 * 64 + lane];
            u32 u3 = F2[(size_t)s3 * 64 + lane];
            a0 += lo2f(u0) + lo2f(u1) + lo2f(u2) + lo2f(u3);
            a1 += hi2f(u0) + hi2f(u1) + hi2f(u2) + hi2f(u3);
        }
        for (; i < num; ++i) {
            u32 u = F2[(size_t)csr[start + i] * 64 + lane];
            a0 += lo2f(u);
            a1 += hi2f(u);
        }
        float sc = 1.0f / (float)(num > 1 ? num : 1);
        a0 *= sc;
        a1 *= sc;
        Aout[(size_t)nd * 64 + lane] = (u32)f2b(a0) | ((u32)f2b(a1) << 16);
    }
}

// ---------------- dual-GEMM: F = act(concat(agg,F) @ Wc + b), IN-PLACE ----------------
// block=256 (4 waves) handles 128 nodes; each wave reads only its own 32 rows
// of Fio before writing them. If outp != nullptr: fused output head, no store.

__global__ void gemm_kernel(const u32* __restrict__ aggb, u32* Fio,
                            const u16* __restrict__ Wcp, const float* __restrict__ biasf,
                            int N, int relu, const float* __restrict__ headw,
                            const int* __restrict__ flags, void* __restrict__ outp) {
    int tid = threadIdx.x;
    int w = tid >> 6;
    int lane = tid & 63;
    int nbase = blockIdx.x * 128;
    int n = lane & 31;
    int q = lane >> 5;
    int rowl = w * 32 + n;
    int node = nbase + rowl;
    int nodeC = (node < N) ? node : (N - 1);
    const u32* aRow = aggb + (size_t)nodeC * 64 + q * 4;
    const u32* fRow = Fio + (size_t)nodeC * 64 + q * 4;

    floatx16 acc0 = 0.0f, acc1 = 0.0f, acc2 = 0.0f, acc3 = 0.0f;

#pragma unroll
    for (int s = 0; s < 16; ++s) {
        const u32* ap = (s < 8) ? (aRow + (size_t)s * 8) : (fRow + (size_t)(s - 8) * 8);
        bf16x8 a = *reinterpret_cast<const bf16x8*>(ap);
        const u16* bp = Wcp + (size_t)((s * 4) * 64 + lane) * 8;
        bf16x8 b0 = *reinterpret_cast<const bf16x8*>(bp);
        bf16x8 b1 = *reinterpret_cast<const bf16x8*>(bp + 64 * 8);
        bf16x8 b2 = *reinterpret_cast<const bf16x8*>(bp + 2 * 64 * 8);
        bf16x8 b3 = *reinterpret_cast<const bf16x8*>(bp + 3 * 64 * 8);
        acc0 = __builtin_amdgcn_mfma_f32_32x32x16_bf16(a, b0, acc0, 0, 0, 0);
        acc1 = __builtin_amdgcn_mfma_f32_32x32x16_bf16(a, b1, acc1, 0, 0, 0);
        acc2 = __builtin_amdgcn_mfma_f32_32x32x16_bf16(a, b2, acc2, 0, 0, 0);
        acc3 = __builtin_amdgcn_mfma_f32_32x32x16_bf16(a, b3, acc3, 0, 0, 0);
    }

    int mbase = nbase + w * 32;
    floatx16 accs[4] = {acc0, acc1, acc2, acc3};
    // C/D: col=lane&31, row=(r&3)+8*(r>>2)+4*(lane>>5)  [verified m74/m101]

    if (outp == nullptr) {
#pragma unroll
        for (int jt = 0; jt < 4; ++jt) {
            int j0 = jt * 32 + n;
            float bf = biasf[j0];
#pragma unroll
            for (int r = 0; r < 16; ++r) {
                int row = (r & 3) + 8 * (r >> 2) + 4 * q;
                int nodeS = mbase + row;
                if (nodeS < N) {
                    float v = accs[jt][r] + bf;
                    if (relu) v = fmaxf(v, 0.0f);
                    u16* dst16 = (u16*)&Fio[(size_t)nodeS * 64];
                    dst16[j0] = f2b(v);
                }
            }
        }
    } else {
        // fused head: out[node] = (h·Wo0 + bo0, h·Wo1 + bo1); h = acc + bl3
        int isbf = flags[1];
#pragma unroll
        for (int r = 0; r < 16; ++r) {
            float p0 = 0.f, p1 = 0.f;
#pragma unroll
            for (int jt = 0; jt < 4; ++jt) {
                int j = jt * 32 + n;
                float v = accs[jt][r] + biasf[j];
                p0 += v * headw[j];
                p1 += v * headw[128 + j];
            }
#pragma unroll
            for (int off = 16; off > 0; off >>= 1) {
                p0 += __shfl_xor(p0, off);
                p1 += __shfl_xor(p1, off);
            }
            if (n == 0) {
                int row = (r & 3) + 8 * (r >> 2) + 4 * q;
                int nodeS = mbase + row;
                if (nodeS < N) {
                    float o0 = p0 + headw[256];  // bo0
                    float o1 = p1 + headw[257];  // bo1
                    if (isbf)
                        ((u32*)outp)[nodeS] = (u32)f2b(o0) | ((u32)f2b(o1) << 16);
                    else
                        ((float2*)outp)[nodeS] = make_float2(o0, o1);
                }
            }
        }
    }
}

extern "C" void kernel_launch(void* const* d_in, const int* in_sizes, int n_in,
                              void* d_out, int out_size, void* d_ws, size_t ws_size,
                              hipStream_t stream) {
    const int N = in_sizes[0] / 128;
    const int E = in_sizes[1] / 2;

    const void* x = d_in[0];
    const int* ei = (const int*)d_in[1];
    const void* Wl[3] = {d_in[2], d_in[5], d_in[8]};
    const void* bl[3] = {d_in[3], d_in[6], d_in[9]};
    const void* Wr[3] = {d_in[4], d_in[7], d_in[10]};
    const void* Wo = d_in[11];
    const void* bo = d_in[12];

    // workspace bump allocator (256B aligned); ~57 MB (proven footprint)
    char* p = (char*)d_ws;
    auto alloc = [&](size_t bytes) -> char* {
        char* r = p;
        p += (bytes + 255) & ~(size_t)255;
        return r;
    };
    int* flags = (int*)alloc(256);
    int* offs = (int*)alloc(((size_t)N + 1) * 4);
    float* smalls = (float*)alloc(642 * 4);
    int* ghist = (int*)alloc(1024 * 4);
    int* bbase = (int*)alloc(1024 * 4);
    int* gcur = (int*)alloc(1024 * 4);
    int* csr = (int*)alloc((size_t)E * 4);
    u16* Wcp = (u16*)alloc((size_t)3 * 4096 * 8 * 2);
    u32* xb = (u32*)alloc((size_t)N * 64 * 4);    // features, updated IN-PLACE per layer
    u32* aggb = (u32*)alloc((size_t)N * 64 * 4);  // agg features; aliased as csrbkt during build
    u32* csrbkt = aggb;                            // dead until layers start
    (void)ws_size;

    const int NB = (N + 255) / 256;           // buckets
    const int gb = (N + 127) / 128;           // gemm blocks
    const int cb = (N * 16 + 255) / 256;      // convert blocks
    const int sb = (E + CH - 1) / CH;         // scatter blocks
    const int ab = ((N + 3) / 4 + 3) / 4;     // agg blocks: 4 nodes/wave, 4 waves/block

    detect_kernel<<<1, 1024, 0, stream>>>(ei, (const u32*)x, flags, ghist);
    bucket_hist_kernel<<<256, 256, 0, stream>>>(ei, E, flags, N, ghist);
    bucket_scan_kernel<<<1, 1024, 0, stream>>>(ghist, bbase, gcur);
    bucket_scatter_kernel<<<sb, 1024, 0, stream>>>(ei, E, flags, N, gcur, csrbkt);
    csr_build_kernel<<<NB, 256, 0, stream>>>(csrbkt, ghist, bbase, N, E, offs, csr);

    convert_x_kernel<<<cb, 256, 0, stream>>>(x, flags, xb, N * 16);
    prep_kernel<<<49, 256, 0, stream>>>(Wl[0], Wr[0], Wl[1], Wr[1], Wl[2], Wr[2],
                                        bl[0], bl[1], bl[2], Wo, bo, flags, Wcp, smalls);

    // layer 1
    agg_kernel<<<ab, 256, 0, stream>>>(xb, offs, csr, aggb, N);
    gemm_kernel<<<gb, 256, 0, stream>>>(aggb, xb, Wcp, smalls, N, 1, nullptr, flags, nullptr);
    // layer 2
    agg_kernel<<<ab, 256, 0, stream>>>(xb, offs, csr, aggb, N);
    gemm_kernel<<<gb, 256, 0, stream>>>(aggb, xb, Wcp + 32768, smalls + 128, N, 1, nullptr, flags, nullptr);
    // layer 3 + fused head
    agg_kernel<<<ab, 256, 0, stream>>>(xb, offs, csr, aggb, N);
    gemm_kernel<<<gb, 256, 0, stream>>>(aggb, xb, Wcp + 65536, smalls + 256, N, 0,
                                        smalls + 384, flags, d_out);
}